// Round 19
// baseline (113.218 us; speedup 1.0000x reference)
//
#include <hip/hip_runtime.h>
#include <hip/hip_bf16.h>

typedef __bf16 bf16x8 __attribute__((ext_vector_type(8)));
typedef float floatx4 __attribute__((ext_vector_type(4)));
typedef unsigned int u32;

#define Bc 4
#define Lc 2048
#define Sc 2048
#define Hc 16
#define Ec 64
#define Dc 64
#define NQT (Lc/64)      /* 32 q-strips of 64 rows */
#define NPAIR (NQT/2)    /* 16 pair-ids */
#define NT (Sc/64)       /* 32 kv tiles */
#define TILEB 8192       /* bytes per bf16 tile image (64x64x2) */
#define WSK ((size_t)Bc*Hc*NT*TILEB)   /* 16 MB for K images */
#define WSNEED (2*WSK)                 /* 32 MB total */
#define QSC 0.18033688011112042f       /* 0.125 * log2(e) */

__device__ __forceinline__ bf16x8 pack8f(const float* f){
  bf16x8 r;
  #pragma unroll
  for (int i=0;i<8;++i) r[i] = (__bf16)f[i];
  return r;
}
__device__ __forceinline__ unsigned pk2(float a, float b){
  union { __bf16 h[2]; unsigned u; } w;
  w.h[0] = (__bf16)a; w.h[1] = (__bf16)b;
  return w.u;
}

// fast HW exp2: single v_exp_f32, no OCML wrapper
__device__ __forceinline__ float fexp2(float x){
  return __builtin_amdgcn_exp2f(x);
}

// DPP lane-permute within each 16-lane row (VALU, no LDS pipe)
template<int CTRL>
__device__ __forceinline__ float dppf(float x){
  return __builtin_bit_cast(float,
    __builtin_amdgcn_update_dpp(0, __builtin_bit_cast(int, x), CTRL, 0xF, 0xF, true));
}
__device__ __forceinline__ float rowmax16(float x){
  x = fmaxf(x, dppf<0xB1>(x));    // xor1
  x = fmaxf(x, dppf<0x4E>(x));    // xor2
  x = fmaxf(x, dppf<0x141>(x));   // xor4 (row_half_mirror)
  x = fmaxf(x, dppf<0x140>(x));   // xor8 (row_mirror)
  return x;
}
__device__ __forceinline__ float rowsum16(float x){
  x += dppf<0xB1>(x);
  x += dppf<0x4E>(x);
  x += dppf<0x141>(x);
  x += dppf<0x140>(x);
  return x;
}

__device__ __forceinline__ void gload16(const void* g, void* l){
  __builtin_amdgcn_global_load_lds(
      (const __attribute__((address_space(1))) u32*)g,
      (__attribute__((address_space(3))) u32*)l, 16, 0, 0);
}

// ---- prepass (r11 verbatim): K,V f32 -> bf16 pre-swizzled LDS tile images ----
__global__ __launch_bounds__(256)
void prep(const float* __restrict__ K, const float* __restrict__ V,
          char* __restrict__ ws)
{
  const int t = blockIdx.x*256 + threadIdx.x;   // 0 .. 2*2^20-1
  if (t < (1<<20)) {
    const int c = t & 7, r = (t>>3) & 63, tile = (t>>9) & 31, h = (t>>14) & 15, b = t>>18;
    const float* src = K + ((size_t)((b*Sc + tile*64 + r))*Hc + h)*Ec + c*8;
    float tmp[8];
    *(float4*)(tmp)   = *(const float4*)(src);
    *(float4*)(tmp+4) = *(const float4*)(src + 4);
    char* dst = ws + (size_t)((b*Hc + h)*NT + tile)*TILEB + r*128 + ((c ^ (r&7))<<4);
    *(bf16x8*)dst = pack8f(tmp);
  } else {
    const int u = t - (1<<20);
    const int d = u & 63, c = (u>>6) & 7, tile = (u>>9) & 31, h = (u>>14) & 15, b = u>>18;
    const float* src = V + ((size_t)((b*Sc + tile*64 + c*8))*Hc + h)*Dc + d;
    bf16x8 v;
    #pragma unroll
    for (int kk=0; kk<8; ++kk) v[kk] = (__bf16)src[(size_t)kk*Hc*Dc];
    char* dst = ws + WSK + (size_t)((b*Hc + h)*NT + tile)*TILEB + d*128 + ((c ^ (d&7))<<4);
    *(bf16x8*)dst = v;
  }
}

// ---- main kernel: r18 + packed b32 P-writes via dpp xor1 exchange ----
__global__ __launch_bounds__(256)
void fa_fwd(const float* __restrict__ Q, const char* __restrict__ ws,
            float* __restrict__ O)
{
  // XCD-contiguous remap (1024 % 8 == 0, bijective)
  int nid = blockIdx.x;
  int bid = (nid & 7) * ((int)gridDim.x >> 3) + (nid >> 3);
  int pid = bid & (NPAIR - 1);
  int h  = (bid >> 4) & (Hc - 1);
  int b  = bid >> 8;

  int tid  = threadIdx.x;
  int w    = tid >> 6;
  int lane = tid & 63;
  int lg   = lane >> 4;   // 0..3
  int lr   = lane & 15;   // 0..15

  __shared__ __align__(16) char Kl[2][64*128];
  __shared__ __align__(16) char Vl[2][64*128];    // transposed: Vt[d][k], swizzled
  __shared__ __align__(16) char Pl[4][16*64*2];   // per-wave P buffer
  char* Pw = Pl[w];

  const char* gK = ws +        (size_t)((b*Hc + h)*NT)*TILEB;
  const char* gV = ws + WSK +  (size_t)((b*Hc + h)*NT)*TILEB;
  const int soff = w*2048 + lane*16;

  const bool odd = lr & 1;
  const int  k0base = lr & ~1;     // even k within 16-group

  // ---- two complementary causal strips: (pid+1) + (32-pid) = 33 tiles, constant ----
  #pragma unroll 1
  for (int pass=0; pass<2; ++pass) {
    const int qt = pass ? (NQT-1-pid) : pid;

    // ---- Q fragments, QSC fold (log2-domain scores); A-layout row=lr, k=32c+8lg+j ----
    const int qrow = qt*64 + w*16 + lr;
    const float* qp = Q + ((size_t)(b*Lc + qrow)*Hc + h)*Ec;
    bf16x8 aq[2];
    {
      float tmp[8];
      #pragma unroll
      for (int c=0; c<2; ++c) {
        *(float4*)(tmp)   = *(const float4*)(qp + c*32 + lg*8);
        *(float4*)(tmp+4) = *(const float4*)(qp + c*32 + lg*8 + 4);
        #pragma unroll
        for (int i=0;i<8;++i) tmp[i] *= QSC;
        aq[c] = pack8f(tmp);
      }
    }

    floatx4 o[4];
    float m[4], lsum[4];
    #pragma unroll
    for (int i=0;i<4;++i){ o[i] = (floatx4){0.f,0.f,0.f,0.f}; m[i] = -3.0e38f; lsum[i] = 0.f; }

    // stage tile 0
    {
      const char* sK = gK + soff;
      const char* sV = gV + soff;
      gload16(sK,        &Kl[0][w*2048]);
      gload16(sK + 1024, &Kl[0][w*2048 + 1024]);
      gload16(sV,        &Vl[0][w*2048]);
      gload16(sV + 1024, &Vl[0][w*2048 + 1024]);
    }
    __syncthreads();   // vmcnt(0) drained: tile 0 resident

    const int nt = qt + 1;
    for (int t = 0; t < nt; ++t) {
      char* Kcur = Kl[t&1];
      char* Vcur = Vl[t&1];

      // ---- issue next tile's staging into the other buffer ----
      if (t+1 < nt) {
        const int nb = (t+1)&1;
        const char* sK = gK + (size_t)(t+1)*TILEB + soff;
        const char* sV = gV + (size_t)(t+1)*TILEB + soff;
        gload16(sK,        &Kl[nb][w*2048]);
        gload16(sK + 1024, &Kl[nb][w*2048 + 1024]);
        gload16(sV,        &Vl[nb][w*2048]);
        gload16(sV + 1024, &Vl[nb][w*2048 + 1024]);
      }

      // ---- QK^T: S[16 q][64 k] (log2-domain scores) ----
      floatx4 s[4];
      #pragma unroll
      for (int nf=0; nf<4; ++nf) {
        int kr = nf*16 + lr;
        unsigned xr = (kr & 7) << 4;
        const char* kp = Kcur + kr*128;
        bf16x8 b0 = *(const bf16x8*)(kp + ((lg*16)      ^ xr));
        bf16x8 b1 = *(const bf16x8*)(kp + ((64 + lg*16) ^ xr));
        floatx4 acc = (floatx4){0.f,0.f,0.f,0.f};
        acc = __builtin_amdgcn_mfma_f32_16x16x32_bf16(aq[0], b0, acc, 0, 0, 0);
        acc = __builtin_amdgcn_mfma_f32_16x16x32_bf16(aq[1], b1, acc, 0, 0, 0);
        s[nf] = acc;
      }

      // ---- causal mask (diagonal tile only) ----
      if (t == qt) {
        #pragma unroll
        for (int nf=0; nf<4; ++nf)
          #pragma unroll
          for (int r=0; r<4; ++r)
            if (nf*16 + lr > w*16 + lg*4 + r) s[nf][r] = -3.0e38f;
      }

      // ---- online softmax (16-lane reductions via DPP, raw v_exp_f32) ----
      float mx[4], rs[4], al[4];
      #pragma unroll
      for (int r=0;r<4;++r) {
        mx[r] = rowmax16(fmaxf(fmaxf(s[0][r], s[1][r]), fmaxf(s[2][r], s[3][r])));
        float mn = fmaxf(m[r], mx[r]);
        al[r] = fexp2(m[r] - mn);
        m[r] = mn;
        rs[r] = 0.f;
      }
      #pragma unroll
      for (int nf=0; nf<4; ++nf)
        #pragma unroll
        for (int r=0;r<4;++r) {
          float p = fexp2(s[nf][r] - m[r]);
          rs[r] += p;
          s[nf][r] = p;
        }
      #pragma unroll
      for (int r=0;r<4;++r) {
        rs[r] = rowsum16(rs[r]);
        lsum[r] = lsum[r]*al[r] + rs[r];
      }
      #pragma unroll
      for (int df=0; df<4; ++df)
        #pragma unroll
        for (int r=0;r<4;++r) o[df][r] *= al[r];

      // ---- P: pack over k via dpp xor1, 8 x b32 writes (was 16 x b16) ----
      // even lane owns k0=nf*16+lr (even); partner (lane^1) owns k0+1.
      // even lane writes rows q=4lg+{0,1}; odd lane writes q=4lg+{2,3}.
      #pragma unroll
      for (int nf=0; nf<4; ++nf) {
        float x0 = dppf<0xB1>(s[nf][0]);   // partner's value, row r=0
        float x1 = dppf<0xB1>(s[nf][1]);
        float x2 = dppf<0xB1>(s[nf][2]);
        float x3 = dppf<0xB1>(s[nf][3]);
        int k0 = nf*16 + k0base;
        int ra = odd ? 2 : 0;              // first row this lane writes
        unsigned w0, w1;
        if (!odd) {                        // own=k0, partner=k0+1
          w0 = pk2(s[nf][0], x0);
          w1 = pk2(s[nf][1], x1);
        } else {                           // partner=k0, own=k0+1
          w0 = pk2(x2, s[nf][2]);
          w1 = pk2(x3, s[nf][3]);
        }
        int q0 = lg*4 + ra;
        *(u32*)(Pw + q0*128     + ((k0*2) ^ ((q0&7)<<4)))     = w0;
        int q1 = q0 + 1;
        *(u32*)(Pw + q1*128     + ((k0*2) ^ ((q1&7)<<4)))     = w1;
      }

      // ---- PV: O[16 q][64 d] += P @ V ----
      {
        unsigned xq = (lr & 7) << 4;
        const char* pp = Pw + lr*128;
        bf16x8 pa0 = *(const bf16x8*)(pp + ((lg*16)      ^ xq));
        bf16x8 pa1 = *(const bf16x8*)(pp + ((64 + lg*16) ^ xq));
        #pragma unroll
        for (int df=0; df<4; ++df) {
          int d = df*16 + lr;
          unsigned xd = (d & 7) << 4;
          const char* vp = Vcur + d*128;
          bf16x8 vb0 = *(const bf16x8*)(vp + ((lg*16)      ^ xd));
          bf16x8 vb1 = *(const bf16x8*)(vp + ((64 + lg*16) ^ xd));
          o[df] = __builtin_amdgcn_mfma_f32_16x16x32_bf16(pa0, vb0, o[df], 0, 0, 0);
          o[df] = __builtin_amdgcn_mfma_f32_16x16x32_bf16(pa1, vb1, o[df], 0, 0, 0);
        }
      }
      __syncthreads();   // drains: next-tile loads landed, all reads of old buffer done
    }

    // ---- epilogue: O / lsum -> global ----
    #pragma unroll
    for (int r=0;r<4;++r) {
      float inv = 1.0f / lsum[r];
      int qg = qt*64 + w*16 + lg*4 + r;
      float* op = O + ((size_t)(b*Lc + qg)*Hc + h)*Dc;
      #pragma unroll
      for (int df=0; df<4; ++df)
        op[df*16 + lr] = o[df][r] * inv;
    }
  } // pass loop
}

// ---- fallback (round-10 style kernel, used only if ws is too small) ----
#define QB 128
#define NQTB (Lc/QB)
#define NPAIRB (NQTB/2)

__global__ __launch_bounds__(256)
void fa_fwd_fb(const float* __restrict__ Q, const float* __restrict__ K,
               const float* __restrict__ V, float* __restrict__ O)
{
  int nid = blockIdx.x;
  int bid = (nid & 7) * ((int)gridDim.x >> 3) + (nid >> 3);
  int pid = bid & (NPAIRB - 1);
  int h  = (bid >> 3) & (Hc - 1);
  int b  = bid >> 7;

  int tid  = threadIdx.x;
  int w    = tid >> 6;
  int lane = tid & 63;
  int lg   = lane >> 4;
  int lr   = lane & 15;

  __shared__ __align__(16) char Kl[2][64*128];
  __shared__ __align__(16) char Vl[2][64*128];
  __shared__ __align__(16) char Pl[4][16*64*2];
  char* Pw = Pl[w];

  const int skr = tid >> 2, seg = tid & 3;
  const int sd  = tid & 63, skb = tid >> 6;
  const unsigned xk = (skr & 7) << 4;
  const unsigned xv = (sd  & 7) << 4;

  const float* Kb = K + ((size_t)(b*Sc)*Hc + h)*Ec;
  const float* Vb = V + ((size_t)(b*Sc)*Hc + h)*Dc;

  float kf[16], vf[16];

  #pragma unroll 1
  for (int pass=0; pass<2; ++pass) {
    const int qtb = pass ? (NQTB-1-pid) : pid;
    const int q0w = qtb*QB + w*32;

    bf16x8 aq[2][2];
    #pragma unroll
    for (int s2=0; s2<2; ++s2) {
      const float* qp = Q + ((size_t)(b*Lc + q0w + s2*16 + lr)*Hc + h)*Ec;
      float tmp[8];
      #pragma unroll
      for (int c=0; c<2; ++c) {
        *(float4*)(tmp)   = *(const float4*)(qp + c*32 + lg*8);
        *(float4*)(tmp+4) = *(const float4*)(qp + c*32 + lg*8 + 4);
        #pragma unroll
        for (int i=0;i<8;++i) tmp[i] *= 0.125f;
        aq[s2][c] = pack8f(tmp);
      }
    }

    floatx4 o[2][4];
    float m[2][4], lsum[2][4];
    #pragma unroll
    for (int s2=0; s2<2; ++s2)
      #pragma unroll
      for (int i=0;i<4;++i){ o[s2][i] = (floatx4){0.f,0.f,0.f,0.f}; m[s2][i] = -3.0e38f; lsum[s2][i] = 0.f; }

    {
      const float* ks = Kb + (size_t)skr*Hc*Ec + seg*16;
      *(float4*)(kf)    = *(const float4*)(ks);
      *(float4*)(kf+4)  = *(const float4*)(ks+4);
      *(float4*)(kf+8)  = *(const float4*)(ks+8);
      *(float4*)(kf+12) = *(const float4*)(ks+12);
      const float* vs = Vb + (size_t)(skb*16)*Hc*Dc + sd;
      #pragma unroll
      for (int i=0;i<16;++i) vf[i] = vs[(size_t)i*Hc*Dc];
    }

    const int nt = 2*qtb + 2;
    for (int t = 0; t < nt; ++t) {
      char* Kcur = Kl[t&1];
      char* Vcur = Vl[t&1];

      *(bf16x8*)(Kcur + skr*128 + ((seg*32)      ^ xk)) = pack8f(kf);
      *(bf16x8*)(Kcur + skr*128 + ((seg*32 + 16) ^ xk)) = pack8f(kf+8);
      *(bf16x8*)(Vcur + sd*128  + ((skb*32)      ^ xv)) = pack8f(vf);
      *(bf16x8*)(Vcur + sd*128  + ((skb*32 + 16) ^ xv)) = pack8f(vf+8);
      __syncthreads();

      if (t+1 < nt) {
        const float* ks = Kb + (size_t)((t+1)*64 + skr)*Hc*Ec + seg*16;
        *(float4*)(kf)    = *(const float4*)(ks);
        *(float4*)(kf+4)  = *(const float4*)(ks+4);
        *(float4*)(kf+8)  = *(const float4*)(ks+8);
        *(float4*)(kf+12) = *(const float4*)(ks+12);
        const float* vs = Vb + (size_t)((t+1)*64 + skb*16)*Hc*Dc + sd;
        #pragma unroll
        for (int i=0;i<16;++i) vf[i] = vs[(size_t)i*Hc*Dc];
      }

      if (t*64 <= q0w + 31) {
        const int t64 = t*64;
        const bool needmask = (t64 + 63 > q0w);

        #pragma unroll
        for (int s2=0; s2<2; ++s2) {
          floatx4 s[4];
          #pragma unroll
          for (int nf=0; nf<4; ++nf) {
            int kr = nf*16 + lr;
            unsigned xr = (kr & 7) << 4;
            const char* kp = Kcur + kr*128;
            bf16x8 b0 = *(const bf16x8*)(kp + ((lg*16)      ^ xr));
            bf16x8 b1 = *(const bf16x8*)(kp + ((64 + lg*16) ^ xr));
            floatx4 acc = (floatx4){0.f,0.f,0.f,0.f};
            acc = __builtin_amdgcn_mfma_f32_16x16x32_bf16(aq[s2][0], b0, acc, 0, 0, 0);
            acc = __builtin_amdgcn_mfma_f32_16x16x32_bf16(aq[s2][1], b1, acc, 0, 0, 0);
            s[nf] = acc;
          }

          if (needmask) {
            const int qq = q0w + s2*16 + lg*4;
            #pragma unroll
            for (int nf=0; nf<4; ++nf)
              #pragma unroll
              for (int r=0; r<4; ++r)
                if (t64 + nf*16 + lr > qq + r) s[nf][r] = -3.0e38f;
          }

          float mx[4], rs[4], al[4];
          #pragma unroll
          for (int r=0;r<4;++r) {
            mx[r] = rowmax16(fmaxf(fmaxf(s[0][r], s[1][r]), fmaxf(s[2][r], s[3][r])));
            float mn = fmaxf(m[s2][r], mx[r]);
            al[r] = __expf(m[s2][r] - mn);
            m[s2][r] = mn;
            rs[r] = 0.f;
          }
          #pragma unroll
          for (int nf=0; nf<4; ++nf)
            #pragma unroll
            for (int r=0;r<4;++r) {
              float p = __expf(s[nf][r] - m[s2][r]);
              rs[r] += p;
              s[nf][r] = p;
            }
          #pragma unroll
          for (int r=0;r<4;++r) {
            rs[r] = rowsum16(rs[r]);
            lsum[s2][r] = lsum[s2][r]*al[r] + rs[r];
          }
          #pragma unroll
          for (int df=0; df<4; ++df)
            #pragma unroll
            for (int r=0;r<4;++r) o[s2][df][r] *= al[r];

          #pragma unroll
          for (int nf=0; nf<4; ++nf)
            #pragma unroll
            for (int r=0;r<4;++r) {
              int q = lg*4 + r;
              int k = nf*16 + lr;
              *(__bf16*)(Pw + q*128 + ((k*2) ^ ((q&7)<<4))) = (__bf16)s[nf][r];
            }

          {
            unsigned xq = (lr & 7) << 4;
            const char* pp = Pw + lr*128;
            bf16x8 pa0 = *(const bf16x8*)(pp + ((lg*16)      ^ xq));
            bf16x8 pa1 = *(const bf16x8*)(pp + ((64 + lg*16) ^ xq));
            #pragma unroll
            for (int df=0; df<4; ++df) {
              int d = df*16 + lr;
              unsigned xd = (d & 7) << 4;
              const char* vp = Vcur + d*128;
              bf16x8 vb0 = *(const bf16x8*)(vp + ((lg*16)      ^ xd));
              bf16x8 vb1 = *(const bf16x8*)(vp + ((64 + lg*16) ^ xd));
              o[s2][df] = __builtin_amdgcn_mfma_f32_16x16x32_bf16(pa0, vb0, o[s2][df], 0, 0, 0);
              o[s2][df] = __builtin_amdgcn_mfma_f32_16x16x32_bf16(pa1, vb1, o[s2][df], 0, 0, 0);
            }
          }
        }
      }
      __syncthreads();
    }

    #pragma unroll
    for (int s2=0; s2<2; ++s2)
      #pragma unroll
      for (int r=0;r<4;++r) {
        float inv = 1.0f / lsum[s2][r];
        int qg = q0w + s2*16 + lg*4 + r;
        float* op = O + ((size_t)(b*Lc + qg)*Hc + h)*Dc;
        #pragma unroll
        for (int df=0; df<4; ++df)
          op[df*16 + lr] = o[s2][df][r] * inv;
      }
  }
}

extern "C" void kernel_launch(void* const* d_in, const int* in_sizes, int n_in,
                              void* d_out, int out_size, void* d_ws, size_t ws_size,
                              hipStream_t stream) {
  const float* Q = (const float*)d_in[0];
  const float* K = (const float*)d_in[1];
  const float* V = (const float*)d_in[2];
  float* O = (float*)d_out;

  if (ws_size >= WSNEED) {
    char* ws = (char*)d_ws;
    prep<<<dim3((2u<<20)/256), dim3(256), 0, stream>>>(K, V, ws);
    fa_fwd<<<dim3(Bc * Hc * NPAIR), dim3(256), 0, stream>>>(Q, ws, O);
  } else {
    fa_fwd_fb<<<dim3(Bc * Hc * NPAIRB), dim3(256), 0, stream>>>(Q, K, V, O);
  }
}

// Round 20
// 106.225 us; speedup vs baseline: 1.0658x; 1.0658x over previous
//
#include <hip/hip_runtime.h>
#include <hip/hip_bf16.h>

typedef __bf16 bf16x8 __attribute__((ext_vector_type(8)));
typedef float floatx4 __attribute__((ext_vector_type(4)));
typedef unsigned int u32;

#define Bc 4
#define Lc 2048
#define Sc 2048
#define Hc 16
#define Ec 64
#define Dc 64
#define NQT (Lc/64)      /* 32 q-strips of 64 rows */
#define NPAIR (NQT/2)    /* 16 pair-ids */
#define NT (Sc/64)       /* 32 kv tiles */
#define TILEB 8192       /* bytes per bf16 tile image (64x64x2) */
#define WSK ((size_t)Bc*Hc*NT*TILEB)   /* 16 MB for K images */
#define WSNEED (2*WSK)                 /* 32 MB total */
#define QSC 0.18033688011112042f       /* 0.125 * log2(e) */
#define THR 11.5f                      /* defer-max threshold (log2 domain) */

__device__ __forceinline__ bf16x8 pack8f(const float* f){
  bf16x8 r;
  #pragma unroll
  for (int i=0;i<8;++i) r[i] = (__bf16)f[i];
  return r;
}

// fast HW exp2: single v_exp_f32, no OCML wrapper
__device__ __forceinline__ float fexp2(float x){
  return __builtin_amdgcn_exp2f(x);
}

// DPP lane-permute within each 16-lane row (VALU, no LDS pipe)
template<int CTRL>
__device__ __forceinline__ float dppf(float x){
  return __builtin_bit_cast(float,
    __builtin_amdgcn_update_dpp(0, __builtin_bit_cast(int, x), CTRL, 0xF, 0xF, true));
}
__device__ __forceinline__ float rowmax16(float x){
  x = fmaxf(x, dppf<0xB1>(x));    // xor1
  x = fmaxf(x, dppf<0x4E>(x));    // xor2
  x = fmaxf(x, dppf<0x141>(x));   // xor4 (row_half_mirror)
  x = fmaxf(x, dppf<0x140>(x));   // xor8 (row_mirror)
  return x;
}
__device__ __forceinline__ float rowsum16(float x){
  x += dppf<0xB1>(x);
  x += dppf<0x4E>(x);
  x += dppf<0x141>(x);
  x += dppf<0x140>(x);
  return x;
}

__device__ __forceinline__ void gload16(const void* g, void* l){
  __builtin_amdgcn_global_load_lds(
      (const __attribute__((address_space(1))) u32*)g,
      (__attribute__((address_space(3))) u32*)l, 16, 0, 0);
}

// ---- prepass (r11 verbatim): K,V f32 -> bf16 pre-swizzled LDS tile images ----
__global__ __launch_bounds__(256)
void prep(const float* __restrict__ K, const float* __restrict__ V,
          char* __restrict__ ws)
{
  const int t = blockIdx.x*256 + threadIdx.x;   // 0 .. 2*2^20-1
  if (t < (1<<20)) {
    const int c = t & 7, r = (t>>3) & 63, tile = (t>>9) & 31, h = (t>>14) & 15, b = t>>18;
    const float* src = K + ((size_t)((b*Sc + tile*64 + r))*Hc + h)*Ec + c*8;
    float tmp[8];
    *(float4*)(tmp)   = *(const float4*)(src);
    *(float4*)(tmp+4) = *(const float4*)(src + 4);
    char* dst = ws + (size_t)((b*Hc + h)*NT + tile)*TILEB + r*128 + ((c ^ (r&7))<<4);
    *(bf16x8*)dst = pack8f(tmp);
  } else {
    const int u = t - (1<<20);
    const int d = u & 63, c = (u>>6) & 7, tile = (u>>9) & 31, h = (u>>14) & 15, b = u>>18;
    const float* src = V + ((size_t)((b*Sc + tile*64 + c*8))*Hc + h)*Dc + d;
    bf16x8 v;
    #pragma unroll
    for (int kk=0; kk<8; ++kk) v[kk] = (__bf16)src[(size_t)kk*Hc*Dc];
    char* dst = ws + WSK + (size_t)((b*Hc + h)*NT + tile)*TILEB + d*128 + ((c ^ (d&7))<<4);
    *(bf16x8*)dst = v;
  }
}

// ---- main kernel: r18 + defer-max (T13) ----
__global__ __launch_bounds__(256)
void fa_fwd(const float* __restrict__ Q, const char* __restrict__ ws,
            float* __restrict__ O)
{
  // XCD-contiguous remap (1024 % 8 == 0, bijective)
  int nid = blockIdx.x;
  int bid = (nid & 7) * ((int)gridDim.x >> 3) + (nid >> 3);
  int pid = bid & (NPAIR - 1);
  int h  = (bid >> 4) & (Hc - 1);
  int b  = bid >> 8;

  int tid  = threadIdx.x;
  int w    = tid >> 6;
  int lane = tid & 63;
  int lg   = lane >> 4;   // 0..3
  int lr   = lane & 15;   // 0..15

  __shared__ __align__(16) char Kl[2][64*128];
  __shared__ __align__(16) char Vl[2][64*128];    // transposed: Vt[d][k], swizzled
  __shared__ __align__(16) char Pl[4][16*64*2];   // per-wave P buffer
  char* Pw = Pl[w];

  const char* gK = ws +        (size_t)((b*Hc + h)*NT)*TILEB;
  const char* gV = ws + WSK +  (size_t)((b*Hc + h)*NT)*TILEB;
  const int soff = w*2048 + lane*16;

  // ---- two complementary causal strips: (pid+1) + (32-pid) = 33 tiles, constant ----
  #pragma unroll 1
  for (int pass=0; pass<2; ++pass) {
    const int qt = pass ? (NQT-1-pid) : pid;

    // ---- Q fragments, QSC fold (log2-domain scores); A-layout row=lr, k=32c+8lg+j ----
    const int qrow = qt*64 + w*16 + lr;
    const float* qp = Q + ((size_t)(b*Lc + qrow)*Hc + h)*Ec;
    bf16x8 aq[2];
    {
      float tmp[8];
      #pragma unroll
      for (int c=0; c<2; ++c) {
        *(float4*)(tmp)   = *(const float4*)(qp + c*32 + lg*8);
        *(float4*)(tmp+4) = *(const float4*)(qp + c*32 + lg*8 + 4);
        #pragma unroll
        for (int i=0;i<8;++i) tmp[i] *= QSC;
        aq[c] = pack8f(tmp);
      }
    }

    floatx4 o[4];
    float m[4], lsum[4];
    #pragma unroll
    for (int i=0;i<4;++i){ o[i] = (floatx4){0.f,0.f,0.f,0.f}; m[i] = -3.0e38f; lsum[i] = 0.f; }

    // stage tile 0
    {
      const char* sK = gK + soff;
      const char* sV = gV + soff;
      gload16(sK,        &Kl[0][w*2048]);
      gload16(sK + 1024, &Kl[0][w*2048 + 1024]);
      gload16(sV,        &Vl[0][w*2048]);
      gload16(sV + 1024, &Vl[0][w*2048 + 1024]);
    }
    __syncthreads();   // vmcnt(0) drained: tile 0 resident

    const int nt = qt + 1;
    for (int t = 0; t < nt; ++t) {
      char* Kcur = Kl[t&1];
      char* Vcur = Vl[t&1];

      // ---- issue next tile's staging into the other buffer ----
      if (t+1 < nt) {
        const int nb = (t+1)&1;
        const char* sK = gK + (size_t)(t+1)*TILEB + soff;
        const char* sV = gV + (size_t)(t+1)*TILEB + soff;
        gload16(sK,        &Kl[nb][w*2048]);
        gload16(sK + 1024, &Kl[nb][w*2048 + 1024]);
        gload16(sV,        &Vl[nb][w*2048]);
        gload16(sV + 1024, &Vl[nb][w*2048 + 1024]);
      }

      // ---- QK^T: S[16 q][64 k] (log2-domain scores) ----
      floatx4 s[4];
      #pragma unroll
      for (int nf=0; nf<4; ++nf) {
        int kr = nf*16 + lr;
        unsigned xr = (kr & 7) << 4;
        const char* kp = Kcur + kr*128;
        bf16x8 b0 = *(const bf16x8*)(kp + ((lg*16)      ^ xr));
        bf16x8 b1 = *(const bf16x8*)(kp + ((64 + lg*16) ^ xr));
        floatx4 acc = (floatx4){0.f,0.f,0.f,0.f};
        acc = __builtin_amdgcn_mfma_f32_16x16x32_bf16(aq[0], b0, acc, 0, 0, 0);
        acc = __builtin_amdgcn_mfma_f32_16x16x32_bf16(aq[1], b1, acc, 0, 0, 0);
        s[nf] = acc;
      }

      // ---- causal mask (diagonal tile only) ----
      if (t == qt) {
        #pragma unroll
        for (int nf=0; nf<4; ++nf)
          #pragma unroll
          for (int r=0; r<4; ++r)
            if (nf*16 + lr > w*16 + lg*4 + r) s[nf][r] = -3.0e38f;
      }

      // ---- row max + defer-max gate (T13): rescale only when max grew > THR ----
      float mx[4];
      float need = -1.f;
      #pragma unroll
      for (int r=0;r<4;++r) {
        mx[r] = rowmax16(fmaxf(fmaxf(s[0][r], s[1][r]), fmaxf(s[2][r], s[3][r])));
        need = fmaxf(need, mx[r] - m[r]);
      }
      if (__any(need > THR)) {
        #pragma unroll
        for (int r=0;r<4;++r) {
          float mn = fmaxf(m[r], mx[r]);
          float al = fexp2(m[r] - mn);
          m[r] = mn;
          lsum[r] *= al;
          #pragma unroll
          for (int df=0; df<4; ++df) o[df][r] *= al;
        }
      }

      // ---- P = exp2(s - m); row-sum ----
      float rs[4] = {0.f,0.f,0.f,0.f};
      #pragma unroll
      for (int nf=0; nf<4; ++nf)
        #pragma unroll
        for (int r=0;r<4;++r) {
          float p = fexp2(s[nf][r] - m[r]);
          rs[r] += p;
          s[nf][r] = p;
        }
      #pragma unroll
      for (int r=0;r<4;++r)
        lsum[r] += rowsum16(rs[r]);

      // ---- P: D-layout regs -> bf16 LDS (per-wave), swizzled ----
      #pragma unroll
      for (int nf=0; nf<4; ++nf)
        #pragma unroll
        for (int r=0;r<4;++r) {
          int q = lg*4 + r;
          int k = nf*16 + lr;
          *(__bf16*)(Pw + q*128 + ((k*2) ^ ((q&7)<<4))) = (__bf16)s[nf][r];
        }

      // ---- PV: O[16 q][64 d] += P @ V ----
      {
        unsigned xq = (lr & 7) << 4;
        const char* pp = Pw + lr*128;
        bf16x8 pa0 = *(const bf16x8*)(pp + ((lg*16)      ^ xq));
        bf16x8 pa1 = *(const bf16x8*)(pp + ((64 + lg*16) ^ xq));
        #pragma unroll
        for (int df=0; df<4; ++df) {
          int d = df*16 + lr;
          unsigned xd = (d & 7) << 4;
          const char* vp = Vcur + d*128;
          bf16x8 vb0 = *(const bf16x8*)(vp + ((lg*16)      ^ xd));
          bf16x8 vb1 = *(const bf16x8*)(vp + ((64 + lg*16) ^ xd));
          o[df] = __builtin_amdgcn_mfma_f32_16x16x32_bf16(pa0, vb0, o[df], 0, 0, 0);
          o[df] = __builtin_amdgcn_mfma_f32_16x16x32_bf16(pa1, vb1, o[df], 0, 0, 0);
        }
      }
      __syncthreads();   // drains: next-tile loads landed, all reads of old buffer done
    }

    // ---- epilogue: O / lsum -> global ----
    #pragma unroll
    for (int r=0;r<4;++r) {
      float inv = 1.0f / lsum[r];
      int qg = qt*64 + w*16 + lg*4 + r;
      float* op = O + ((size_t)(b*Lc + qg)*Hc + h)*Dc;
      #pragma unroll
      for (int df=0; df<4; ++df)
        op[df*16 + lr] = o[df][r] * inv;
    }
  } // pass loop
}

// ---- fallback (round-10 style kernel, used only if ws is too small) ----
#define QB 128
#define NQTB (Lc/QB)
#define NPAIRB (NQTB/2)

__global__ __launch_bounds__(256)
void fa_fwd_fb(const float* __restrict__ Q, const float* __restrict__ K,
               const float* __restrict__ V, float* __restrict__ O)
{
  int nid = blockIdx.x;
  int bid = (nid & 7) * ((int)gridDim.x >> 3) + (nid >> 3);
  int pid = bid & (NPAIRB - 1);
  int h  = (bid >> 3) & (Hc - 1);
  int b  = bid >> 7;

  int tid  = threadIdx.x;
  int w    = tid >> 6;
  int lane = tid & 63;
  int lg   = lane >> 4;
  int lr   = lane & 15;

  __shared__ __align__(16) char Kl[2][64*128];
  __shared__ __align__(16) char Vl[2][64*128];
  __shared__ __align__(16) char Pl[4][16*64*2];
  char* Pw = Pl[w];

  const int skr = tid >> 2, seg = tid & 3;
  const int sd  = tid & 63, skb = tid >> 6;
  const unsigned xk = (skr & 7) << 4;
  const unsigned xv = (sd  & 7) << 4;

  const float* Kb = K + ((size_t)(b*Sc)*Hc + h)*Ec;
  const float* Vb = V + ((size_t)(b*Sc)*Hc + h)*Dc;

  float kf[16], vf[16];

  #pragma unroll 1
  for (int pass=0; pass<2; ++pass) {
    const int qtb = pass ? (NQTB-1-pid) : pid;
    const int q0w = qtb*QB + w*32;

    bf16x8 aq[2][2];
    #pragma unroll
    for (int s2=0; s2<2; ++s2) {
      const float* qp = Q + ((size_t)(b*Lc + q0w + s2*16 + lr)*Hc + h)*Ec;
      float tmp[8];
      #pragma unroll
      for (int c=0; c<2; ++c) {
        *(float4*)(tmp)   = *(const float4*)(qp + c*32 + lg*8);
        *(float4*)(tmp+4) = *(const float4*)(qp + c*32 + lg*8 + 4);
        #pragma unroll
        for (int i=0;i<8;++i) tmp[i] *= 0.125f;
        aq[s2][c] = pack8f(tmp);
      }
    }

    floatx4 o[2][4];
    float m[2][4], lsum[2][4];
    #pragma unroll
    for (int s2=0; s2<2; ++s2)
      #pragma unroll
      for (int i=0;i<4;++i){ o[s2][i] = (floatx4){0.f,0.f,0.f,0.f}; m[s2][i] = -3.0e38f; lsum[s2][i] = 0.f; }

    {
      const float* ks = Kb + (size_t)skr*Hc*Ec + seg*16;
      *(float4*)(kf)    = *(const float4*)(ks);
      *(float4*)(kf+4)  = *(const float4*)(ks+4);
      *(float4*)(kf+8)  = *(const float4*)(ks+8);
      *(float4*)(kf+12) = *(const float4*)(ks+12);
      const float* vs = Vb + (size_t)(skb*16)*Hc*Dc + sd;
      #pragma unroll
      for (int i=0;i<16;++i) vf[i] = vs[(size_t)i*Hc*Dc];
    }

    const int nt = 2*qtb + 2;
    for (int t = 0; t < nt; ++t) {
      char* Kcur = Kl[t&1];
      char* Vcur = Vl[t&1];

      *(bf16x8*)(Kcur + skr*128 + ((seg*32)      ^ xk)) = pack8f(kf);
      *(bf16x8*)(Kcur + skr*128 + ((seg*32 + 16) ^ xk)) = pack8f(kf+8);
      *(bf16x8*)(Vcur + sd*128  + ((skb*32)      ^ xv)) = pack8f(vf);
      *(bf16x8*)(Vcur + sd*128  + ((skb*32 + 16) ^ xv)) = pack8f(vf+8);
      __syncthreads();

      if (t+1 < nt) {
        const float* ks = Kb + (size_t)((t+1)*64 + skr)*Hc*Ec + seg*16;
        *(float4*)(kf)    = *(const float4*)(ks);
        *(float4*)(kf+4)  = *(const float4*)(ks+4);
        *(float4*)(kf+8)  = *(const float4*)(ks+8);
        *(float4*)(kf+12) = *(const float4*)(ks+12);
        const float* vs = Vb + (size_t)((t+1)*64 + skb*16)*Hc*Dc + sd;
        #pragma unroll
        for (int i=0;i<16;++i) vf[i] = vs[(size_t)i*Hc*Dc];
      }

      if (t*64 <= q0w + 31) {
        const int t64 = t*64;
        const bool needmask = (t64 + 63 > q0w);

        #pragma unroll
        for (int s2=0; s2<2; ++s2) {
          floatx4 s[4];
          #pragma unroll
          for (int nf=0; nf<4; ++nf) {
            int kr = nf*16 + lr;
            unsigned xr = (kr & 7) << 4;
            const char* kp = Kcur + kr*128;
            bf16x8 b0 = *(const bf16x8*)(kp + ((lg*16)      ^ xr));
            bf16x8 b1 = *(const bf16x8*)(kp + ((64 + lg*16) ^ xr));
            floatx4 acc = (floatx4){0.f,0.f,0.f,0.f};
            acc = __builtin_amdgcn_mfma_f32_16x16x32_bf16(aq[s2][0], b0, acc, 0, 0, 0);
            acc = __builtin_amdgcn_mfma_f32_16x16x32_bf16(aq[s2][1], b1, acc, 0, 0, 0);
            s[nf] = acc;
          }

          if (needmask) {
            const int qq = q0w + s2*16 + lg*4;
            #pragma unroll
            for (int nf=0; nf<4; ++nf)
              #pragma unroll
              for (int r=0; r<4; ++r)
                if (t64 + nf*16 + lr > qq + r) s[nf][r] = -3.0e38f;
          }

          float mx[4], rs[4], al[4];
          #pragma unroll
          for (int r=0;r<4;++r) {
            mx[r] = rowmax16(fmaxf(fmaxf(s[0][r], s[1][r]), fmaxf(s[2][r], s[3][r])));
            float mn = fmaxf(m[s2][r], mx[r]);
            al[r] = __expf(m[s2][r] - mn);
            m[s2][r] = mn;
            rs[r] = 0.f;
          }
          #pragma unroll
          for (int nf=0; nf<4; ++nf)
            #pragma unroll
            for (int r=0;r<4;++r) {
              float p = __expf(s[nf][r] - m[s2][r]);
              rs[r] += p;
              s[nf][r] = p;
            }
          #pragma unroll
          for (int r=0;r<4;++r) {
            rs[r] = rowsum16(rs[r]);
            lsum[s2][r] = lsum[s2][r]*al[r] + rs[r];
          }
          #pragma unroll
          for (int df=0; df<4; ++df)
            #pragma unroll
            for (int r=0;r<4;++r) o[s2][df][r] *= al[r];

          #pragma unroll
          for (int nf=0; nf<4; ++nf)
            #pragma unroll
            for (int r=0;r<4;++r) {
              int q = lg*4 + r;
              int k = nf*16 + lr;
              *(__bf16*)(Pw + q*128 + ((k*2) ^ ((q&7)<<4))) = (__bf16)s[nf][r];
            }

          {
            unsigned xq = (lr & 7) << 4;
            const char* pp = Pw + lr*128;
            bf16x8 pa0 = *(const bf16x8*)(pp + ((lg*16)      ^ xq));
            bf16x8 pa1 = *(const bf16x8*)(pp + ((64 + lg*16) ^ xq));
            #pragma unroll
            for (int df=0; df<4; ++df) {
              int d = df*16 + lr;
              unsigned xd = (d & 7) << 4;
              const char* vp = Vcur + d*128;
              bf16x8 vb0 = *(const bf16x8*)(vp + ((lg*16)      ^ xd));
              bf16x8 vb1 = *(const bf16x8*)(vp + ((64 + lg*16) ^ xd));
              o[s2][df] = __builtin_amdgcn_mfma_f32_16x16x32_bf16(pa0, vb0, o[s2][df], 0, 0, 0);
              o[s2][df] = __builtin_amdgcn_mfma_f32_16x16x32_bf16(pa1, vb1, o[s2][df], 0, 0, 0);
            }
          }
        }
      }
      __syncthreads();
    }

    #pragma unroll
    for (int s2=0; s2<2; ++s2)
      #pragma unroll
      for (int r=0;r<4;++r) {
        float inv = 1.0f / lsum[s2][r];
        int qg = q0w + s2*16 + lg*4 + r;
        float* op = O + ((size_t)(b*Lc + qg)*Hc + h)*Dc;
        #pragma unroll
        for (int df=0; df<4; ++df)
          op[df*16 + lr] = o[s2][df][r] * inv;
      }
  }
}

extern "C" void kernel_launch(void* const* d_in, const int* in_sizes, int n_in,
                              void* d_out, int out_size, void* d_ws, size_t ws_size,
                              hipStream_t stream) {
  const float* Q = (const float*)d_in[0];
  const float* K = (const float*)d_in[1];
  const float* V = (const float*)d_in[2];
  float* O = (float*)d_out;

  if (ws_size >= WSNEED) {
    char* ws = (char*)d_ws;
    prep<<<dim3((2u<<20)/256), dim3(256), 0, stream>>>(K, V, ws);
    fa_fwd<<<dim3(Bc * Hc * NPAIR), dim3(256), 0, stream>>>(Q, ws, O);
  } else {
    fa_fwd_fb<<<dim3(Bc * Hc * NPAIRB), dim3(256), 0, stream>>>(Q, K, V, O);
  }
}